// Round 1
// baseline (326.778 us; speedup 1.0000x reference)
//
#include <hip/hip_runtime.h>
#include <hip/hip_bf16.h>
#include <stdint.h>

typedef __bf16 bf16x8 __attribute__((ext_vector_type(8)));
typedef float f32x4 __attribute__((ext_vector_type(4)));

static __device__ __forceinline__ unsigned short f2bf(float x) {
    union { float f; unsigned u; } v; v.f = x;
    unsigned r = v.u + 0x7FFFu + ((v.u >> 16) & 1u);  // round-to-nearest-even
    return (unsigned short)(r >> 16);
}

static __device__ __forceinline__ void gload_lds16(const void* g, void* l) {
    auto gp = (const unsigned int __attribute__((address_space(1)))*)(reinterpret_cast<uintptr_t>(g));
    auto lp = (unsigned int __attribute__((address_space(3)))*)(reinterpret_cast<uintptr_t>(l));
    __builtin_amdgcn_global_load_lds(gp, lp, 16, 0, 0);
}

// ---------- Kernel A: attn = softmax(morphosyn @ W_affix), stored bf16, k-block XOR-swizzled ----------
__global__ void attn_kernel(const float* __restrict__ morphosyn,
                            const float* __restrict__ W,
                            unsigned short* __restrict__ attn_sw) {
    const int b = blockIdx.x;
    const int t = threadIdx.x;
    __shared__ float ms[128];
    __shared__ float red[4];
    if (t < 128) ms[t] = morphosyn[b * 128 + t];
    __syncthreads();
    float acc0 = 0.f, acc1 = 0.f;
    #pragma unroll 8
    for (int dm = 0; dm < 128; ++dm) {
        float m = ms[dm];
        acc0 = fmaf(m, W[dm * 512 + t], acc0);
        acc1 = fmaf(m, W[dm * 512 + t + 256], acc1);
    }
    const int lane = t & 63, wid = t >> 6;
    float mx = fmaxf(acc0, acc1);
    #pragma unroll
    for (int o = 32; o; o >>= 1) mx = fmaxf(mx, __shfl_xor(mx, o));
    if (lane == 0) red[wid] = mx;
    __syncthreads();
    mx = fmaxf(fmaxf(red[0], red[1]), fmaxf(red[2], red[3]));
    __syncthreads();
    float e0 = __expf(acc0 - mx), e1 = __expf(acc1 - mx);
    float sm = e0 + e1;
    #pragma unroll
    for (int o = 32; o; o >>= 1) sm += __shfl_xor(sm, o);
    if (lane == 0) red[wid] = sm;
    __syncthreads();
    sm = red[0] + red[1] + red[2] + red[3];
    const float inv = 1.0f / sm;
    const int swz = (b >> 2) & 3;
    #pragma unroll
    for (int h = 0; h < 2; ++h) {
        int v = t + h * 256;
        int ae = (v >> 5) * 32 + ((((v >> 3) & 3) ^ swz) << 3) + (v & 7);
        attn_sw[b * 512 + ae] = f2bf((h ? e1 : e0) * inv);
    }
}

// ---------- Kernel B: wC[b,n] = cumsum_n( sum_ijk a_i b_j f_k softmax(logits[ijbk,:]) ) ----------
__global__ void wc_kernel(const float* __restrict__ logits,
                          const float* __restrict__ alpha,
                          const float* __restrict__ beta,
                          const float* __restrict__ phi,
                          float* __restrict__ wC) {
    const int b = blockIdx.x;
    const int t = threadIdx.x;  // position n
    const int lane = t & 63, wid = t >> 6;
    __shared__ float red[4];
    __shared__ float wsum[4];

    // mixture weights (redundant per block; trivial)
    float a0 = alpha[0], a1 = alpha[1];
    float am = fmaxf(a0, a1);
    float ea0 = __expf(a0 - am), ea1 = __expf(a1 - am);
    float as = ea0 + ea1; ea0 /= as; ea1 /= as;
    float b0 = beta[0], b1 = beta[1];
    float bm = fmaxf(b0, b1);
    float eb0 = __expf(b0 - bm), eb1 = __expf(b1 - bm);
    float bs = eb0 + eb1; eb0 /= bs; eb1 /= bs;
    float p[5];
    float pm = -1e30f;
    #pragma unroll
    for (int k = 0; k < 5; ++k) { p[k] = phi[k]; pm = fmaxf(pm, p[k]); }
    float ps = 0.f;
    #pragma unroll
    for (int k = 0; k < 5; ++k) { p[k] = __expf(p[k] - pm); ps += p[k]; }
    #pragma unroll
    for (int k = 0; k < 5; ++k) p[k] /= ps;
    const float wa[2] = {ea0, ea1}, wb[2] = {eb0, eb1};

    float s = 0.f;
    for (int i = 0; i < 2; ++i)
        for (int j = 0; j < 2; ++j)
            for (int k = 0; k < 5; ++k) {
                size_t off = ((size_t)(((i * 2 + j) * 1024 + b) * 5 + k)) * 256 + t;
                float x = logits[off];
                float mx = x;
                #pragma unroll
                for (int o = 32; o; o >>= 1) mx = fmaxf(mx, __shfl_xor(mx, o));
                if (lane == 0) red[wid] = mx;
                __syncthreads();
                mx = fmaxf(fmaxf(red[0], red[1]), fmaxf(red[2], red[3]));
                __syncthreads();
                float e = __expf(x - mx);
                float sm = e;
                #pragma unroll
                for (int o = 32; o; o >>= 1) sm += __shfl_xor(sm, o);
                if (lane == 0) red[wid] = sm;
                __syncthreads();
                sm = red[0] + red[1] + red[2] + red[3];
                __syncthreads();
                s += (wa[i] * wb[j] * p[k]) * (e / sm);
            }

    // inclusive scan over the 256 positions
    float v = s;
    #pragma unroll
    for (int o = 1; o < 64; o <<= 1) {
        float u = __shfl_up(v, o);
        if (lane >= o) v += u;
    }
    if (lane == 63) wsum[wid] = v;
    __syncthreads();
    float offv = 0.f;
    for (int w2 = 0; w2 < wid; ++w2) offv += wsum[w2];
    wC[b * 256 + t] = v + offv;
}

// ---------- Kernel C: fused GEMM  out[b,n'] = stem*(1-wC) + (attn @ vocab)*wC ----------
// M=1024 (b), N'=65536 (d*256+n), K=512 (v). 128x128 tile, BK=32, 4 waves, 16x16x32 bf16 MFMA.
__global__ void gemm_kernel(const unsigned short* __restrict__ attn_sw,
                            const float* __restrict__ vocab,
                            const float* __restrict__ stem,
                            const float* __restrict__ wC,
                            float* __restrict__ out) {
    const int tile_m = blockIdx.x & 7;       // fast dim = m  -> 8 m-tiles share vocab panel in L2
    const int tile_n = blockIdx.x >> 3;
    const int m0 = tile_m << 7;
    const int n0 = tile_n << 7;
    const int t = threadIdx.x;
    const int lane = t & 63;
    const int wv = t >> 6;
    const int wm = wv >> 1, wn = wv & 1;

    __shared__ unsigned short Asl[128 * 32];  // A[m][k], k-blocks XOR-swizzled by (m>>2)&3 (pre-swizzled in ws)
    __shared__ unsigned short Bsl[128 * 32];  // B[n][k], k-blocks XOR-swizzled by (n>>2)&3

    f32x4 acc[4][4];
    const f32x4 z = {0.f, 0.f, 0.f, 0.f};
    #pragma unroll
    for (int i = 0; i < 4; ++i)
        #pragma unroll
        for (int j = 0; j < 4; ++j) acc[i][j] = z;

    const unsigned short* a_base = attn_sw + ((size_t)m0 << 9);
    const int q = lane >> 4;
    const int rl = lane & 15;

    for (int ks = 0; ks < 16; ++ks) {
        // ---- stage A: 128x32 bf16 via global_load_lds (linear dest, source pre-swizzled) ----
        #pragma unroll
        for (int it = 0; it < 2; ++it) {
            int idx = it * 256 + t;          // 0..511 : 16B chunks
            int r = idx >> 2, blk = idx & 3;
            gload_lds16(a_base + r * 512 + ks * 32 + blk * 8, Asl + idx * 8);
        }
        // ---- stage B: 32x128 f32 -> bf16, transposed to [n][k] with k-block XOR swizzle ----
        #pragma unroll
        for (int it = 0; it < 2; ++it) {
            int lin = it * 256 + t;          // 0..511
            int pair = lin >> 5;             // 16 k-pairs
            int chunk = lin & 31;            // 32 n-chunks of 4
            int k = pair * 2;
            const float* g0 = vocab + (size_t)(ks * 32 + k) * 65536 + n0 + chunk * 4;
            float4 v0 = *(const float4*)g0;
            float4 v1 = *(const float4*)(g0 + 65536);
            #pragma unroll
            for (int j = 0; j < 4; ++j) {
                int n = chunk * 4 + j;
                unsigned d = (unsigned)f2bf((&v0.x)[j]) | ((unsigned)f2bf((&v1.x)[j]) << 16);
                int ae = n * 32 + ((((k >> 3) ^ ((n >> 2) & 3))) << 3) + (k & 7);
                *(unsigned*)((char*)Bsl + ae * 2) = d;
            }
        }
        __syncthreads();
        // ---- fragments ----
        bf16x8 af[4], bf[4];
        #pragma unroll
        for (int f = 0; f < 4; ++f) {
            int r = wm * 64 + f * 16 + rl;
            af[f] = *(const bf16x8*)((const char*)Asl + r * 64 + ((q ^ ((r >> 2) & 3)) << 4));
            int c = wn * 64 + f * 16 + rl;
            bf[f] = *(const bf16x8*)((const char*)Bsl + c * 64 + ((q ^ ((c >> 2) & 3)) << 4));
        }
        __syncthreads();
        #pragma unroll
        for (int fm = 0; fm < 4; ++fm)
            #pragma unroll
            for (int fn = 0; fn < 4; ++fn)
                acc[fm][fn] = __builtin_amdgcn_mfma_f32_16x16x32_bf16(af[fm], bf[fn], acc[fm][fn], 0, 0, 0);
    }

    // ---- epilogue: out = stem + (acc - stem) * wC ----
    #pragma unroll
    for (int fm = 0; fm < 4; ++fm) {
        int rbase = m0 + wm * 64 + fm * 16 + ((lane >> 4) << 2);
        #pragma unroll
        for (int fn = 0; fn < 4; ++fn) {
            int c = n0 + wn * 64 + fn * 16 + (lane & 15);
            #pragma unroll
            for (int i = 0; i < 4; ++i) {
                int b = rbase + i;
                float w = wC[(b << 8) + (c & 255)];
                size_t o = ((size_t)b << 16) + (size_t)c;
                float sv = stem[o];
                out[o] = sv + (acc[fm][fn][i] - sv) * w;
            }
        }
    }
}

extern "C" void kernel_launch(void* const* d_in, const int* in_sizes, int n_in,
                              void* d_out, int out_size, void* d_ws, size_t ws_size,
                              hipStream_t stream) {
    const float* stem    = (const float*)d_in[0];
    const float* morpho  = (const float*)d_in[1];
    const float* logits  = (const float*)d_in[2];
    const float* W       = (const float*)d_in[3];
    const float* vocab   = (const float*)d_in[4];
    const float* alpha   = (const float*)d_in[5];
    const float* beta    = (const float*)d_in[6];
    const float* phi     = (const float*)d_in[7];
    float* out = (float*)d_out;

    unsigned short* attn_sw = (unsigned short*)d_ws;                 // 1024*512*2 = 1 MB
    float* wC = (float*)((char*)d_ws + (1 << 20));                   // 1024*256*4 = 1 MB

    attn_kernel<<<1024, 256, 0, stream>>>(morpho, W, attn_sw);
    wc_kernel<<<1024, 256, 0, stream>>>(logits, alpha, beta, phi, wC);
    gemm_kernel<<<4096, 256, 0, stream>>>(attn_sw, vocab, stem, wC, out);
}

// Round 2
// 325.982 us; speedup vs baseline: 1.0024x; 1.0024x over previous
//
#include <hip/hip_runtime.h>
#include <hip/hip_bf16.h>
#include <stdint.h>

typedef __bf16 bf16x8 __attribute__((ext_vector_type(8)));
typedef float f32x4 __attribute__((ext_vector_type(4)));

static __device__ __forceinline__ unsigned short f2bf(float x) {
    union { float f; unsigned u; } v; v.f = x;
    unsigned r = v.u + 0x7FFFu + ((v.u >> 16) & 1u);  // round-to-nearest-even
    return (unsigned short)(r >> 16);
}

static __device__ __forceinline__ void gload_lds16(const void* g, void* l) {
    auto gp = (const unsigned int __attribute__((address_space(1)))*)(reinterpret_cast<uintptr_t>(g));
    auto lp = (unsigned int __attribute__((address_space(3)))*)(reinterpret_cast<uintptr_t>(l));
    __builtin_amdgcn_global_load_lds(gp, lp, 16, 0, 0);
}

// ---------- Kernel A: attn = softmax(morphosyn @ W_affix), stored bf16, k-block XOR-swizzled ----------
__global__ void attn_kernel(const float* __restrict__ morphosyn,
                            const float* __restrict__ W,
                            unsigned short* __restrict__ attn_sw) {
    const int b = blockIdx.x;
    const int t = threadIdx.x;
    __shared__ float ms[128];
    __shared__ float red[4];
    if (t < 128) ms[t] = morphosyn[b * 128 + t];
    __syncthreads();
    float acc0 = 0.f, acc1 = 0.f;
    #pragma unroll 8
    for (int dm = 0; dm < 128; ++dm) {
        float m = ms[dm];
        acc0 = fmaf(m, W[dm * 512 + t], acc0);
        acc1 = fmaf(m, W[dm * 512 + t + 256], acc1);
    }
    const int lane = t & 63, wid = t >> 6;
    float mx = fmaxf(acc0, acc1);
    #pragma unroll
    for (int o = 32; o; o >>= 1) mx = fmaxf(mx, __shfl_xor(mx, o));
    if (lane == 0) red[wid] = mx;
    __syncthreads();
    mx = fmaxf(fmaxf(red[0], red[1]), fmaxf(red[2], red[3]));
    __syncthreads();
    float e0 = __expf(acc0 - mx), e1 = __expf(acc1 - mx);
    float sm = e0 + e1;
    #pragma unroll
    for (int o = 32; o; o >>= 1) sm += __shfl_xor(sm, o);
    if (lane == 0) red[wid] = sm;
    __syncthreads();
    sm = red[0] + red[1] + red[2] + red[3];
    const float inv = 1.0f / sm;
    const int swz = (b >> 2) & 3;
    #pragma unroll
    for (int h = 0; h < 2; ++h) {
        int v = t + h * 256;
        int ae = (v >> 5) * 32 + ((((v >> 3) & 3) ^ swz) << 3) + (v & 7);
        attn_sw[b * 512 + ae] = f2bf((h ? e1 : e0) * inv);
    }
}

// ---------- Kernel B: wC[b,n] = cumsum_n( sum_ijk a_i b_j f_k softmax(logits[ijbk,:]) ) ----------
__global__ void wc_kernel(const float* __restrict__ logits,
                          const float* __restrict__ alpha,
                          const float* __restrict__ beta,
                          const float* __restrict__ phi,
                          float* __restrict__ wC) {
    const int b = blockIdx.x;
    const int t = threadIdx.x;  // position n
    const int lane = t & 63, wid = t >> 6;
    __shared__ float red[4];
    __shared__ float wsum[4];

    float a0 = alpha[0], a1 = alpha[1];
    float am = fmaxf(a0, a1);
    float ea0 = __expf(a0 - am), ea1 = __expf(a1 - am);
    float as = ea0 + ea1; ea0 /= as; ea1 /= as;
    float b0 = beta[0], b1 = beta[1];
    float bm = fmaxf(b0, b1);
    float eb0 = __expf(b0 - bm), eb1 = __expf(b1 - bm);
    float bs = eb0 + eb1; eb0 /= bs; eb1 /= bs;
    float p[5];
    float pm = -1e30f;
    #pragma unroll
    for (int k = 0; k < 5; ++k) { p[k] = phi[k]; pm = fmaxf(pm, p[k]); }
    float ps = 0.f;
    #pragma unroll
    for (int k = 0; k < 5; ++k) { p[k] = __expf(p[k] - pm); ps += p[k]; }
    #pragma unroll
    for (int k = 0; k < 5; ++k) p[k] /= ps;
    const float wa[2] = {ea0, ea1}, wb[2] = {eb0, eb1};

    float s = 0.f;
    for (int i = 0; i < 2; ++i)
        for (int j = 0; j < 2; ++j)
            for (int k = 0; k < 5; ++k) {
                size_t off = ((size_t)(((i * 2 + j) * 1024 + b) * 5 + k)) * 256 + t;
                float x = logits[off];
                float mx = x;
                #pragma unroll
                for (int o = 32; o; o >>= 1) mx = fmaxf(mx, __shfl_xor(mx, o));
                if (lane == 0) red[wid] = mx;
                __syncthreads();
                mx = fmaxf(fmaxf(red[0], red[1]), fmaxf(red[2], red[3]));
                __syncthreads();
                float e = __expf(x - mx);
                float sm = e;
                #pragma unroll
                for (int o = 32; o; o >>= 1) sm += __shfl_xor(sm, o);
                if (lane == 0) red[wid] = sm;
                __syncthreads();
                sm = red[0] + red[1] + red[2] + red[3];
                __syncthreads();
                s += (wa[i] * wb[j] * p[k]) * (e / sm);
            }

    float v = s;
    #pragma unroll
    for (int o = 1; o < 64; o <<= 1) {
        float u = __shfl_up(v, o);
        if (lane >= o) v += u;
    }
    if (lane == 63) wsum[wid] = v;
    __syncthreads();
    float offv = 0.f;
    for (int w2 = 0; w2 < wid; ++w2) offv += wsum[w2];
    wC[b * 256 + t] = v + offv;
}

// ---------- Kernel T: vocab f32 [v][n'] -> bf16 Bt[n'][v], k-block XOR-swizzled per row ----------
// Grid: 4096 blocks x 256 threads; each block does n' tile of 16, full K=512.
__global__ void conv_kernel(const float* __restrict__ vocab, unsigned short* __restrict__ Bt) {
    const int n0 = blockIdx.x * 16;
    const int t = threadIdx.x;
    __shared__ unsigned int T[16 * 256];  // [n][v/2] dwords (v,v+1 packed), 16 KB
    #pragma unroll
    for (int it = 0; it < 4; ++it) {
        int p = it * 256 + t;       // 0..1023
        int v = (p >> 2) * 2;       // even v
        int col4 = p & 3;
        const float* g0 = vocab + (size_t)v * 65536 + n0 + col4 * 4;
        float4 a = *(const float4*)g0;
        float4 c = *(const float4*)(g0 + 65536);
        #pragma unroll
        for (int j = 0; j < 4; ++j) {
            int n = col4 * 4 + j;
            unsigned d = (unsigned)f2bf((&a.x)[j]) | ((unsigned)f2bf((&c.x)[j]) << 16);
            T[n * 256 + (v >> 1)] = d;
        }
    }
    __syncthreads();
    #pragma unroll
    for (int it = 0; it < 4; ++it) {
        int q = it * 256 + t;   // 0..1023 : 16B chunks (8 bf16 = one swizzle block)
        int r = q >> 6, c = q & 63;
        int swz = ((n0 + r) >> 2) & 3;
        int dc = (c & ~3) | ((c & 3) ^ swz);
        uint4 d = *(const uint4*)(&T[r * 256 + c * 4]);
        *(uint4*)(Bt + (size_t)(n0 + r) * 512 + dc * 8) = d;
    }
}

// ---------- Kernel C (fast): fused GEMM, both operands via global_load_lds ----------
__global__ void gemm_kernel(const unsigned short* __restrict__ attn_sw,
                            const unsigned short* __restrict__ Bt,
                            const float* __restrict__ stem,
                            const float* __restrict__ wC,
                            float* __restrict__ out) {
    // XCD-aware swizzle: all 8 m-tiles of a vocab panel + 64 consecutive n-panels per XCD.
    const int bid = blockIdx.x;
    const int slot = bid >> 3;
    const int tile_n = ((bid & 7) << 6) + (slot >> 3);
    const int tile_m = slot & 7;
    const int m0 = tile_m << 7;
    const int n0 = tile_n << 7;
    const int t = threadIdx.x;
    const int lane = t & 63;
    const int wv = t >> 6;
    const int wm = wv >> 1, wn = wv & 1;

    __shared__ unsigned short Asl[128 * 32];  // A[m][k], swizzled (source pre-swizzled)
    __shared__ unsigned short Bsl[128 * 32];  // B[n][k], swizzled (source pre-swizzled)

    f32x4 acc[4][4];
    const f32x4 z = {0.f, 0.f, 0.f, 0.f};
    #pragma unroll
    for (int i = 0; i < 4; ++i)
        #pragma unroll
        for (int j = 0; j < 4; ++j) acc[i][j] = z;

    const unsigned short* a_base = attn_sw + ((size_t)m0 << 9);
    const unsigned short* b_base = Bt + ((size_t)n0 << 9);
    const int q = lane >> 4;
    const int rl = lane & 15;

    for (int ks = 0; ks < 16; ++ks) {
        #pragma unroll
        for (int it = 0; it < 2; ++it) {
            int idx = it * 256 + t;          // 0..511 : 16B chunks
            int r = idx >> 2, blk = idx & 3;
            gload_lds16(a_base + r * 512 + ks * 32 + blk * 8, Asl + idx * 8);
        }
        #pragma unroll
        for (int it = 0; it < 2; ++it) {
            int idx = it * 256 + t;
            int r = idx >> 2, blk = idx & 3;
            gload_lds16(b_base + r * 512 + ks * 32 + blk * 8, Bsl + idx * 8);
        }
        __syncthreads();
        bf16x8 af[4], bfr[4];
        #pragma unroll
        for (int f = 0; f < 4; ++f) {
            int r = wm * 64 + f * 16 + rl;
            af[f] = *(const bf16x8*)((const char*)Asl + r * 64 + ((q ^ ((r >> 2) & 3)) << 4));
            int c = wn * 64 + f * 16 + rl;
            bfr[f] = *(const bf16x8*)((const char*)Bsl + c * 64 + ((q ^ ((c >> 2) & 3)) << 4));
        }
        __syncthreads();
        #pragma unroll
        for (int fm = 0; fm < 4; ++fm)
            #pragma unroll
            for (int fn = 0; fn < 4; ++fn)
                acc[fm][fn] = __builtin_amdgcn_mfma_f32_16x16x32_bf16(af[fm], bfr[fn], acc[fm][fn], 0, 0, 0);
    }

    #pragma unroll
    for (int fm = 0; fm < 4; ++fm) {
        int rbase = m0 + wm * 64 + fm * 16 + ((lane >> 4) << 2);
        #pragma unroll
        for (int fn = 0; fn < 4; ++fn) {
            int c = n0 + wn * 64 + fn * 16 + (lane & 15);
            #pragma unroll
            for (int i = 0; i < 4; ++i) {
                int b = rbase + i;
                float w = wC[(b << 8) + (c & 255)];
                size_t o = ((size_t)b << 16) + (size_t)c;
                float sv = stem[o];
                out[o] = sv + (acc[fm][fn][i] - sv) * w;
            }
        }
    }
}

// ---------- Kernel C (fallback, ws too small): in-kernel convert+transpose ----------
__global__ void gemm_fb(const unsigned short* __restrict__ attn_sw,
                        const float* __restrict__ vocab,
                        const float* __restrict__ stem,
                        const float* __restrict__ wC,
                        float* __restrict__ out) {
    const int tile_m = blockIdx.x & 7;
    const int tile_n = blockIdx.x >> 3;
    const int m0 = tile_m << 7;
    const int n0 = tile_n << 7;
    const int t = threadIdx.x;
    const int lane = t & 63;
    const int wv = t >> 6;
    const int wm = wv >> 1, wn = wv & 1;

    __shared__ unsigned short Asl[128 * 32];
    __shared__ unsigned short Bsl[128 * 32];

    f32x4 acc[4][4];
    const f32x4 z = {0.f, 0.f, 0.f, 0.f};
    #pragma unroll
    for (int i = 0; i < 4; ++i)
        #pragma unroll
        for (int j = 0; j < 4; ++j) acc[i][j] = z;

    const unsigned short* a_base = attn_sw + ((size_t)m0 << 9);
    const int q = lane >> 4;
    const int rl = lane & 15;

    for (int ks = 0; ks < 16; ++ks) {
        #pragma unroll
        for (int it = 0; it < 2; ++it) {
            int idx = it * 256 + t;
            int r = idx >> 2, blk = idx & 3;
            gload_lds16(a_base + r * 512 + ks * 32 + blk * 8, Asl + idx * 8);
        }
        #pragma unroll
        for (int it = 0; it < 2; ++it) {
            int lin = it * 256 + t;
            int pair = lin >> 5;
            int chunk = lin & 31;
            int k = pair * 2;
            const float* g0 = vocab + (size_t)(ks * 32 + k) * 65536 + n0 + chunk * 4;
            float4 v0 = *(const float4*)g0;
            float4 v1 = *(const float4*)(g0 + 65536);
            #pragma unroll
            for (int j = 0; j < 4; ++j) {
                int n = chunk * 4 + j;
                unsigned d = (unsigned)f2bf((&v0.x)[j]) | ((unsigned)f2bf((&v1.x)[j]) << 16);
                int ae = n * 32 + ((((k >> 3) ^ ((n >> 2) & 3))) << 3) + (k & 7);
                *(unsigned*)((char*)Bsl + ae * 2) = d;
            }
        }
        __syncthreads();
        bf16x8 af[4], bfr[4];
        #pragma unroll
        for (int f = 0; f < 4; ++f) {
            int r = wm * 64 + f * 16 + rl;
            af[f] = *(const bf16x8*)((const char*)Asl + r * 64 + ((q ^ ((r >> 2) & 3)) << 4));
            int c = wn * 64 + f * 16 + rl;
            bfr[f] = *(const bf16x8*)((const char*)Bsl + c * 64 + ((q ^ ((c >> 2) & 3)) << 4));
        }
        __syncthreads();
        #pragma unroll
        for (int fm = 0; fm < 4; ++fm)
            #pragma unroll
            for (int fn = 0; fn < 4; ++fn)
                acc[fm][fn] = __builtin_amdgcn_mfma_f32_16x16x32_bf16(af[fm], bfr[fn], acc[fm][fn], 0, 0, 0);
    }

    #pragma unroll
    for (int fm = 0; fm < 4; ++fm) {
        int rbase = m0 + wm * 64 + fm * 16 + ((lane >> 4) << 2);
        #pragma unroll
        for (int fn = 0; fn < 4; ++fn) {
            int c = n0 + wn * 64 + fn * 16 + (lane & 15);
            #pragma unroll
            for (int i = 0; i < 4; ++i) {
                int b = rbase + i;
                float w = wC[(b << 8) + (c & 255)];
                size_t o = ((size_t)b << 16) + (size_t)c;
                float sv = stem[o];
                out[o] = sv + (acc[fm][fn][i] - sv) * w;
            }
        }
    }
}

extern "C" void kernel_launch(void* const* d_in, const int* in_sizes, int n_in,
                              void* d_out, int out_size, void* d_ws, size_t ws_size,
                              hipStream_t stream) {
    const float* stem    = (const float*)d_in[0];
    const float* morpho  = (const float*)d_in[1];
    const float* logits  = (const float*)d_in[2];
    const float* W       = (const float*)d_in[3];
    const float* vocab   = (const float*)d_in[4];
    const float* alpha   = (const float*)d_in[5];
    const float* beta    = (const float*)d_in[6];
    const float* phi     = (const float*)d_in[7];
    float* out = (float*)d_out;

    unsigned short* attn_sw = (unsigned short*)d_ws;                 // 1 MB
    float* wC = (float*)((char*)d_ws + (1 << 20));                   // 1 MB
    unsigned short* Bt = (unsigned short*)((char*)d_ws + (2 << 20)); // 64 MB (bf16 vocab^T)

    const size_t need = (size_t)(2 << 20) + (size_t)64 * 1024 * 1024;

    attn_kernel<<<1024, 256, 0, stream>>>(morpho, W, attn_sw);
    wc_kernel<<<1024, 256, 0, stream>>>(logits, alpha, beta, phi, wC);
    if (ws_size >= need) {
        conv_kernel<<<4096, 256, 0, stream>>>(vocab, Bt);
        gemm_kernel<<<4096, 256, 0, stream>>>(attn_sw, Bt, stem, wC, out);
    } else {
        gemm_fb<<<4096, 256, 0, stream>>>(attn_sw, vocab, stem, wC, out);
    }
}

// Round 3
// 296.921 us; speedup vs baseline: 1.1006x; 1.0979x over previous
//
#include <hip/hip_runtime.h>
#include <hip/hip_bf16.h>
#include <stdint.h>

typedef __bf16 bf16x8 __attribute__((ext_vector_type(8)));
typedef float f32x4 __attribute__((ext_vector_type(4)));

static __device__ __forceinline__ unsigned short f2bf(float x) {
    union { float f; unsigned u; } v; v.f = x;
    unsigned r = v.u + 0x7FFFu + ((v.u >> 16) & 1u);  // round-to-nearest-even
    return (unsigned short)(r >> 16);
}

static __device__ __forceinline__ void gload_lds16(const void* g, void* l) {
    auto gp = (const unsigned int __attribute__((address_space(1)))*)(reinterpret_cast<uintptr_t>(g));
    auto lp = (unsigned int __attribute__((address_space(3)))*)(reinterpret_cast<uintptr_t>(l));
    __builtin_amdgcn_global_load_lds(gp, lp, 16, 0, 0);
}

// ---------- Kernel A: attn = softmax(morphosyn @ W_affix), stored bf16, k-block XOR-swizzled ----------
__global__ void attn_kernel(const float* __restrict__ morphosyn,
                            const float* __restrict__ W,
                            unsigned short* __restrict__ attn_sw) {
    const int b = blockIdx.x;
    const int t = threadIdx.x;
    __shared__ float ms[128];
    __shared__ float red[4];
    if (t < 128) ms[t] = morphosyn[b * 128 + t];
    __syncthreads();
    float acc0 = 0.f, acc1 = 0.f;
    #pragma unroll 8
    for (int dm = 0; dm < 128; ++dm) {
        float m = ms[dm];
        acc0 = fmaf(m, W[dm * 512 + t], acc0);
        acc1 = fmaf(m, W[dm * 512 + t + 256], acc1);
    }
    const int lane = t & 63, wid = t >> 6;
    float mx = fmaxf(acc0, acc1);
    #pragma unroll
    for (int o = 32; o; o >>= 1) mx = fmaxf(mx, __shfl_xor(mx, o));
    if (lane == 0) red[wid] = mx;
    __syncthreads();
    mx = fmaxf(fmaxf(red[0], red[1]), fmaxf(red[2], red[3]));
    __syncthreads();
    float e0 = __expf(acc0 - mx), e1 = __expf(acc1 - mx);
    float sm = e0 + e1;
    #pragma unroll
    for (int o = 32; o; o >>= 1) sm += __shfl_xor(sm, o);
    if (lane == 0) red[wid] = sm;
    __syncthreads();
    sm = red[0] + red[1] + red[2] + red[3];
    const float inv = 1.0f / sm;
    const int swz = (b >> 2) & 3;
    #pragma unroll
    for (int h = 0; h < 2; ++h) {
        int v = t + h * 256;
        int ae = (v >> 5) * 32 + ((((v >> 3) & 3) ^ swz) << 3) + (v & 7);
        attn_sw[b * 512 + ae] = f2bf((h ? e1 : e0) * inv);
    }
}

// ---------- Kernel B: wC[b,n] = cumsum_n( sum_ijk a_i b_j f_k softmax(logits[ijbk,:]) ) ----------
// Wave-parallel: each of 4 waves owns 5 of the 20 (i,j,k) slices; wave-local reductions only.
__global__ void wc_kernel(const float* __restrict__ logits,
                          const float* __restrict__ alpha,
                          const float* __restrict__ beta,
                          const float* __restrict__ phi,
                          float* __restrict__ wC) {
    const int b = blockIdx.x;
    const int t = threadIdx.x;
    const int lane = t & 63, wid = t >> 6;
    __shared__ float part[4][256];
    __shared__ float wsum[4];

    float a0 = alpha[0], a1 = alpha[1];
    float am = fmaxf(a0, a1);
    float ea0 = __expf(a0 - am), ea1 = __expf(a1 - am);
    float as = ea0 + ea1;
    float b0 = beta[0], b1 = beta[1];
    float bm = fmaxf(b0, b1);
    float eb0 = __expf(b0 - bm), eb1 = __expf(b1 - bm);
    float bs = eb0 + eb1;
    float p[5];
    float pm = -1e30f;
    #pragma unroll
    for (int k = 0; k < 5; ++k) { p[k] = phi[k]; pm = fmaxf(pm, p[k]); }
    float ps = 0.f;
    #pragma unroll
    for (int k = 0; k < 5; ++k) { p[k] = __expf(p[k] - pm); ps += p[k]; }
    const float wa[2] = {ea0 / as, ea1 / as}, wb[2] = {eb0 / bs, eb1 / bs};

    f32x4 accv = {0.f, 0.f, 0.f, 0.f};
    #pragma unroll
    for (int s5 = 0; s5 < 5; ++s5) {
        int sl = wid * 5 + s5;           // 0..19
        int i = sl >= 10;
        int j = (sl / 5) & 1;
        int k = sl - (sl / 5) * 5;
        const float* base = logits + ((size_t)(((i * 2 + j) * 1024 + b) * 5 + k)) * 256;
        f32x4 x = *(const f32x4*)(base + lane * 4);
        float mx = fmaxf(fmaxf(x[0], x[1]), fmaxf(x[2], x[3]));
        #pragma unroll
        for (int o = 32; o; o >>= 1) mx = fmaxf(mx, __shfl_xor(mx, o));
        f32x4 e;
        float sm = 0.f;
        #pragma unroll
        for (int r = 0; r < 4; ++r) { e[r] = __expf(x[r] - mx); sm += e[r]; }
        #pragma unroll
        for (int o = 32; o; o >>= 1) sm += __shfl_xor(sm, o);
        float w = wa[i] * wb[j] * (p[k] / ps) / sm;
        #pragma unroll
        for (int r = 0; r < 4; ++r) accv[r] += w * e[r];
    }
    *(f32x4*)&part[wid][lane * 4] = accv;
    __syncthreads();
    float v = part[0][t] + part[1][t] + part[2][t] + part[3][t];
    #pragma unroll
    for (int o = 1; o < 64; o <<= 1) {
        float u = __shfl_up(v, o);
        if (lane >= o) v += u;
    }
    if (lane == 63) wsum[wid] = v;
    __syncthreads();
    float offv = 0.f;
    for (int w2 = 0; w2 < wid; ++w2) offv += wsum[w2];
    wC[b * 256 + t] = v + offv;
}

// ---------- Kernel T: vocab f32 [v][n'] -> bf16 Bt[n'][v], k-block XOR-swizzled per row ----------
__global__ void conv_kernel(const float* __restrict__ vocab, unsigned short* __restrict__ Bt) {
    const int n0 = blockIdx.x * 16;
    const int t = threadIdx.x;
    __shared__ unsigned int T[16 * 256];  // [n][v/2] dwords
    #pragma unroll
    for (int it = 0; it < 4; ++it) {
        int p = it * 256 + t;
        int v = (p >> 2) * 2;
        int col4 = p & 3;
        const float* g0 = vocab + (size_t)v * 65536 + n0 + col4 * 4;
        float4 a = *(const float4*)g0;
        float4 c = *(const float4*)(g0 + 65536);
        #pragma unroll
        for (int j = 0; j < 4; ++j) {
            int n = col4 * 4 + j;
            unsigned d = (unsigned)f2bf((&a.x)[j]) | ((unsigned)f2bf((&c.x)[j]) << 16);
            T[n * 256 + (v >> 1)] = d;
        }
    }
    __syncthreads();
    #pragma unroll
    for (int it = 0; it < 4; ++it) {
        int qq = it * 256 + t;
        int r = qq >> 6, c = qq & 63;
        int swz = ((n0 + r) >> 2) & 3;
        int dc = (c & ~3) | ((c & 3) ^ swz);
        uint4 d = *(const uint4*)(&T[r * 256 + c * 4]);
        *(uint4*)(Bt + (size_t)(n0 + r) * 512 + dc * 8) = d;
    }
}

// ---------- Kernel C (fast): fused GEMM, depth-2 pipelined, counted vmcnt ----------
__global__ void gemm_kernel(const unsigned short* __restrict__ attn_sw,
                            const unsigned short* __restrict__ Bt,
                            const float* __restrict__ stem,
                            const float* __restrict__ wC,
                            float* __restrict__ out) {
    const int bid = blockIdx.x;
    const int slot = bid >> 3;
    const int tile_n = ((bid & 7) << 6) + (slot >> 3);
    const int tile_m = slot & 7;
    const int m0 = tile_m << 7;
    const int n0 = tile_n << 7;
    const int t = threadIdx.x;
    const int lane = t & 63;
    const int wv = t >> 6;
    const int wm = wv >> 1, wn = wv & 1;
    const int q = lane >> 4;
    const int rl = lane & 15;

    __shared__ __align__(16) char smem[49152];  // 3 bufs x (A 8KB + B 8KB)
    unsigned short* ldsAB = (unsigned short*)smem;

    f32x4 acc[4][4];
    const f32x4 z = {0.f, 0.f, 0.f, 0.f};
    #pragma unroll
    for (int i = 0; i < 4; ++i)
        #pragma unroll
        for (int j = 0; j < 4; ++j) acc[i][j] = z;

    const unsigned short* a_base = attn_sw + ((size_t)m0 << 9);
    const unsigned short* b_base = Bt + ((size_t)n0 << 9);

#define STAGE(T) { \
    unsigned short* dA_ = ldsAB + ((T) % 3) * 8192; \
    unsigned short* dB_ = dA_ + 4096; \
    { int idx_ = t;        int r_ = idx_ >> 2, blk_ = idx_ & 3; \
      gload_lds16(a_base + r_ * 512 + (T) * 32 + blk_ * 8, dA_ + idx_ * 8); \
      gload_lds16(b_base + r_ * 512 + (T) * 32 + blk_ * 8, dB_ + idx_ * 8); } \
    { int idx_ = 256 + t;  int r_ = idx_ >> 2, blk_ = idx_ & 3; \
      gload_lds16(a_base + r_ * 512 + (T) * 32 + blk_ * 8, dA_ + idx_ * 8); \
      gload_lds16(b_base + r_ * 512 + (T) * 32 + blk_ * 8, dB_ + idx_ * 8); } }

#define KSTEP(T, VM) { \
    if ((T) + 2 < 16) STAGE((T) + 2); \
    asm volatile("s_waitcnt vmcnt(" #VM ")" ::: "memory"); \
    __builtin_amdgcn_s_barrier(); \
    const unsigned short* As_ = ldsAB + ((T) % 3) * 8192; \
    const unsigned short* Bs_ = As_ + 4096; \
    bf16x8 af[4], bfr[4]; \
    _Pragma("unroll") \
    for (int f = 0; f < 4; ++f) { \
        int r_ = wm * 64 + f * 16 + rl; \
        af[f] = *(const bf16x8*)((const char*)As_ + r_ * 64 + ((q ^ ((r_ >> 2) & 3)) << 4)); \
        int c_ = wn * 64 + f * 16 + rl; \
        bfr[f] = *(const bf16x8*)((const char*)Bs_ + c_ * 64 + ((q ^ ((c_ >> 2) & 3)) << 4)); \
    } \
    _Pragma("unroll") \
    for (int fm_ = 0; fm_ < 4; ++fm_) \
        _Pragma("unroll") \
        for (int fn_ = 0; fn_ < 4; ++fn_) \
            acc[fm_][fn_] = __builtin_amdgcn_mfma_f32_16x16x32_bf16(af[fm_], bfr[fn_], acc[fm_][fn_], 0, 0, 0); \
    __builtin_amdgcn_s_barrier(); }

    STAGE(0); STAGE(1);
    KSTEP(0, 8);  KSTEP(1, 8);  KSTEP(2, 8);  KSTEP(3, 8);
    KSTEP(4, 8);  KSTEP(5, 8);  KSTEP(6, 8);  KSTEP(7, 8);
    KSTEP(8, 8);  KSTEP(9, 8);  KSTEP(10, 8); KSTEP(11, 8);
    KSTEP(12, 8); KSTEP(13, 8); KSTEP(14, 4); KSTEP(15, 0);
#undef STAGE
#undef KSTEP

    // ---- epilogue: acc -> LDS (stride-132) -> float4 RMW with stem/wC ----
    float* cs = (float*)smem;
    #pragma unroll
    for (int s = 0; s < 4; ++s) {
        if (wm == (s >> 1)) {
            #pragma unroll
            for (int fh = 0; fh < 2; ++fh) {
                int fm = (s & 1) * 2 + fh;
                #pragma unroll
                for (int fn = 0; fn < 4; ++fn) {
                    int cl = wn * 64 + fn * 16 + rl;
                    #pragma unroll
                    for (int i = 0; i < 4; ++i)
                        cs[(fh * 16 + q * 4 + i) * 132 + cl] = acc[fm][fn][i];
                }
            }
        }
        __syncthreads();
        {
            int row = t >> 3, col0 = (t & 7) * 16;
            int b = m0 + s * 32 + row;
            size_t gbase = ((size_t)b << 16) + (size_t)n0 + col0;
            const float* wrow = wC + ((size_t)b << 8) + (n0 & 255);
            #pragma unroll
            for (int v4 = 0; v4 < 4; ++v4) {
                f32x4 cv = *(const f32x4*)&cs[row * 132 + col0 + v4 * 4];
                f32x4 sv = *(const f32x4*)&stem[gbase + v4 * 4];
                f32x4 wv = *(const f32x4*)&wrow[col0 + v4 * 4];
                f32x4 ov;
                #pragma unroll
                for (int jj = 0; jj < 4; ++jj)
                    ov[jj] = sv[jj] + (cv[jj] - sv[jj]) * wv[jj];
                *(f32x4*)&out[gbase + v4 * 4] = ov;
            }
        }
        __syncthreads();
    }
}

// ---------- Kernel C (fallback, ws too small): in-kernel convert+transpose ----------
__global__ void gemm_fb(const unsigned short* __restrict__ attn_sw,
                        const float* __restrict__ vocab,
                        const float* __restrict__ stem,
                        const float* __restrict__ wC,
                        float* __restrict__ out) {
    const int tile_m = blockIdx.x & 7;
    const int tile_n = blockIdx.x >> 3;
    const int m0 = tile_m << 7;
    const int n0 = tile_n << 7;
    const int t = threadIdx.x;
    const int lane = t & 63;
    const int wv = t >> 6;
    const int wm = wv >> 1, wn = wv & 1;

    __shared__ unsigned short Asl[128 * 32];
    __shared__ unsigned short Bsl[128 * 32];

    f32x4 acc[4][4];
    const f32x4 z = {0.f, 0.f, 0.f, 0.f};
    #pragma unroll
    for (int i = 0; i < 4; ++i)
        #pragma unroll
        for (int j = 0; j < 4; ++j) acc[i][j] = z;

    const unsigned short* a_base = attn_sw + ((size_t)m0 << 9);
    const int q = lane >> 4;
    const int rl = lane & 15;

    for (int ks = 0; ks < 16; ++ks) {
        #pragma unroll
        for (int it = 0; it < 2; ++it) {
            int idx = it * 256 + t;
            int r = idx >> 2, blk = idx & 3;
            gload_lds16(a_base + r * 512 + ks * 32 + blk * 8, Asl + idx * 8);
        }
        #pragma unroll
        for (int it = 0; it < 2; ++it) {
            int lin = it * 256 + t;
            int pair = lin >> 5;
            int chunk = lin & 31;
            int k = pair * 2;
            const float* g0 = vocab + (size_t)(ks * 32 + k) * 65536 + n0 + chunk * 4;
            float4 v0 = *(const float4*)g0;
            float4 v1 = *(const float4*)(g0 + 65536);
            #pragma unroll
            for (int j = 0; j < 4; ++j) {
                int n = chunk * 4 + j;
                unsigned d = (unsigned)f2bf((&v0.x)[j]) | ((unsigned)f2bf((&v1.x)[j]) << 16);
                int ae = n * 32 + ((((k >> 3) ^ ((n >> 2) & 3))) << 3) + (k & 7);
                *(unsigned*)((char*)Bsl + ae * 2) = d;
            }
        }
        __syncthreads();
        bf16x8 af[4], bfr[4];
        #pragma unroll
        for (int f = 0; f < 4; ++f) {
            int r = wm * 64 + f * 16 + rl;
            af[f] = *(const bf16x8*)((const char*)Asl + r * 64 + ((q ^ ((r >> 2) & 3)) << 4));
            int c = wn * 64 + f * 16 + rl;
            bfr[f] = *(const bf16x8*)((const char*)Bsl + c * 64 + ((q ^ ((c >> 2) & 3)) << 4));
        }
        __syncthreads();
        #pragma unroll
        for (int fm = 0; fm < 4; ++fm)
            #pragma unroll
            for (int fn = 0; fn < 4; ++fn)
                acc[fm][fn] = __builtin_amdgcn_mfma_f32_16x16x32_bf16(af[fm], bfr[fn], acc[fm][fn], 0, 0, 0);
    }

    #pragma unroll
    for (int fm = 0; fm < 4; ++fm) {
        int rbase = m0 + wm * 64 + fm * 16 + ((lane >> 4) << 2);
        #pragma unroll
        for (int fn = 0; fn < 4; ++fn) {
            int c = n0 + wn * 64 + fn * 16 + (lane & 15);
            #pragma unroll
            for (int i = 0; i < 4; ++i) {
                int b = rbase + i;
                float w = wC[(b << 8) + (c & 255)];
                size_t o = ((size_t)b << 16) + (size_t)c;
                float sv = stem[o];
                out[o] = sv + (acc[fm][fn][i] - sv) * w;
            }
        }
    }
}

extern "C" void kernel_launch(void* const* d_in, const int* in_sizes, int n_in,
                              void* d_out, int out_size, void* d_ws, size_t ws_size,
                              hipStream_t stream) {
    const float* stem    = (const float*)d_in[0];
    const float* morpho  = (const float*)d_in[1];
    const float* logits  = (const float*)d_in[2];
    const float* W       = (const float*)d_in[3];
    const float* vocab   = (const float*)d_in[4];
    const float* alpha   = (const float*)d_in[5];
    const float* beta    = (const float*)d_in[6];
    const float* phi     = (const float*)d_in[7];
    float* out = (float*)d_out;

    unsigned short* attn_sw = (unsigned short*)d_ws;                 // 1 MB
    float* wC = (float*)((char*)d_ws + (1 << 20));                   // 1 MB
    unsigned short* Bt = (unsigned short*)((char*)d_ws + (2 << 20)); // 64 MB

    const size_t need = (size_t)(2 << 20) + (size_t)64 * 1024 * 1024;

    attn_kernel<<<1024, 256, 0, stream>>>(morpho, W, attn_sw);
    wc_kernel<<<1024, 256, 0, stream>>>(logits, alpha, beta, phi, wC);
    if (ws_size >= need) {
        conv_kernel<<<4096, 256, 0, stream>>>(vocab, Bt);
        gemm_kernel<<<4096, 256, 0, stream>>>(attn_sw, Bt, stem, wC, out);
    } else {
        gemm_fb<<<4096, 256, 0, stream>>>(attn_sw, vocab, stem, wC, out);
    }
}